// Round 17
// baseline (556.450 us; speedup 1.0000x reference)
//
#include <hip/hip_runtime.h>
#include <math.h>

#define GRID_SZ 128
#define NC 196
#define NC4 49                // NC/4 float4 per row
#define G2 (GRID_SZ*GRID_SZ)  // 16384
#define BPB 64                // blocks per batch in accum
#define SLOTS 128             // LDS table slots (one per gx, gy=gz=0)
#define SLOTF4 224            // floats per slot: 4 rows x 56 (transposed, den at [49])
#define AW 16                 // waves per accum block (1024 threads)

// =========================================================================
// K1: streaming accumulation.
// Block = 16 waves (1024 thr), 1 block/CU (112 KB LDS table).
// float4 row loads: lane l holds channels 4l..4l+3 (1 VMEM inst/point).
// Hot keys (gy==gz==0, ~97.7%):
//   gx==0   (~50%) -> per-wave register accumulator
//   gx==127 (~16%) -> per-wave register accumulator
//   gx==cache tag  -> sticky register cache
//   cache miss     -> flush to LDS table (transposed [4][56] layout,
//                     stride-4B per lane -> conflict-free ds_add)
// Tail (~2.3%): direct global atomics to full per-plane bins.
// =========================================================================

__global__ __launch_bounds__(1024, 1) void lds_accum_kernel(
    const float* __restrict__ gs, const float* __restrict__ sb,
    float* __restrict__ nw, float* __restrict__ dn,
    float* __restrict__ tblout, int N) {
    __shared__ float tbl[SLOTS * SLOTF4];   // 114688 B

    const int tid = threadIdx.x;
    const int lane = tid & 63;
    const int widx = tid >> 6;

    for (int i = tid; i < SLOTS * SLOTF4; i += 1024) tbl[i] = 0.f;
    __syncthreads();

    const int b = blockIdx.x / BPB;
    const int blk = blockIdx.x % BPB;
    const int strip = N / BPB;            // points per block (2048)
    const int cnt = strip / AW;           // points per wave (128)
    const long long p0 = (long long)b * N + (long long)blk * strip
                       + (long long)widx * cnt;

    const float lo0 = sb[0], hi0 = sb[1];
    const float lo1 = sb[2], hi1 = sb[3];
    const float lo2 = sb[4], hi2 = sb[5];
    const float s0 = 2.0f / (hi0 - lo0);
    const float s1 = 2.0f / (hi1 - lo1);
    const float s2 = 2.0f / (hi2 - lo2);

    const float4 f40 = make_float4(0.f, 0.f, 0.f, 0.f);
    const float4* rows4 = (const float4*)(gs + (size_t)p0 * NC);
    const bool ld = (lane < NC4);

    #define LOADP(J, V) { V = ld ? rows4[(size_t)(J) * NC4 + lane] : f40; }

    #define LDSFLUSH(TAG, A, D)                                        \
        {                                                              \
            float* s_ = tbl + (TAG) * SLOTF4;                          \
            if (ld) {                                                  \
                atomicAdd(s_ + lane, (A).x);                           \
                atomicAdd(s_ + 56 + lane, (A).y);                      \
                atomicAdd(s_ + 112 + lane, (A).z);                     \
                atomicAdd(s_ + 168 + lane, (A).w);                     \
            }                                                          \
            if (lane == 0) atomicAdd(s_ + 49, (D));                    \
        }

    float4 vA, vB, vC, vD;
    const int i1 = (cnt > 1) ? 1 : 0;
    const int i2 = (cnt > 2) ? 2 : 0;
    const int i3 = (cnt > 3) ? 3 : 0;
    LOADP(0, vA); LOADP(i1, vB); LOADP(i2, vC); LOADP(i3, vD);

    float4 z = f40, z127 = f40, cc = f40;
    float zd = 0.f, z127d = 0.f, ccd = 0.f;
    int ctag = -1;

    #define CONSUME(V)                                                       \
        {                                                                    \
            const float hx = __shfl((V).x, 0);                               \
            const float hy = __shfl((V).y, 0);                               \
            const float hz = __shfl((V).z, 0);                               \
            const float hw = __shfl((V).w, 0);                               \
            const float cnx = (hx - lo0) * s0 - 1.0f;                        \
            const float cny = (hy - lo1) * s1 - 1.0f;                        \
            const float cnz = (hz - lo2) * s2 - 1.0f;                        \
            int gx = (int)((cnx * 0.5f + 0.5f) * 127.0f);                    \
            int gy = (int)((cny * 0.5f + 0.5f) * 127.0f);                    \
            int gz = (int)((cnz * 0.5f + 0.5f) * 127.0f);                    \
            gx = min(127, max(0, gx));                                       \
            gy = min(127, max(0, gy));                                       \
            gz = min(127, max(0, gz));                                       \
            const float alpha = 1.0f / (1.0f + __expf(-hw));                 \
            float4 vv = (V);                                                 \
            if (lane == 0) { vv.x = cnx; vv.y = cny; vv.z = cnz; }           \
            const float4 av = make_float4(vv.x * alpha, vv.y * alpha,        \
                                          vv.z * alpha, vv.w * alpha);       \
            if ((gy | gz) == 0) {                                            \
                if (gx == 0) {                                               \
                    z.x += av.x; z.y += av.y; z.z += av.z; z.w += av.w;      \
                    zd += alpha;                                             \
                } else if (gx == 127) {                                      \
                    z127.x += av.x; z127.y += av.y;                          \
                    z127.z += av.z; z127.w += av.w;                          \
                    z127d += alpha;                                          \
                } else if (gx == ctag) {                                     \
                    cc.x += av.x; cc.y += av.y; cc.z += av.z; cc.w += av.w;  \
                    ccd += alpha;                                            \
                } else {                                                     \
                    if (ctag > 0) LDSFLUSH(ctag, cc, ccd);                   \
                    ctag = gx; cc = av; ccd = alpha;                         \
                }                                                            \
            } else {                                                         \
                const int cells[3] = { gx * GRID_SZ + gy, gx * GRID_SZ + gz, \
                                       gy * GRID_SZ + gz };                  \
                _Pragma("unroll")                                            \
                for (int p = 0; p < 3; ++p) {                                \
                    const int bin = (b * 3 + p) * G2 + cells[p];             \
                    float* dst = nw + (size_t)bin * NC + 4 * lane;           \
                    if (ld) {                                                \
                        unsafeAtomicAdd(dst + 0, av.x);                      \
                        unsafeAtomicAdd(dst + 1, av.y);                      \
                        unsafeAtomicAdd(dst + 2, av.z);                      \
                        unsafeAtomicAdd(dst + 3, av.w);                      \
                    }                                                        \
                    if (lane == 0) unsafeAtomicAdd(dn + bin, alpha);         \
                }                                                            \
            }                                                                \
        }

    for (int j = 0; j < cnt; j += 2) {
        float4 vE, vF;
        const int j4 = (j + 4 < cnt) ? j + 4 : cnt - 1;
        const int j5 = (j + 5 < cnt) ? j + 5 : cnt - 1;
        LOADP(j4, vE); LOADP(j5, vF);

        CONSUME(vA);
        CONSUME(vB);

        vA = vC; vB = vD; vC = vE; vD = vF;
    }
    #undef CONSUME
    #undef LOADP

    if (ctag > 0) LDSFLUSH(ctag, cc, ccd);
    LDSFLUSH(127, z127, z127d);
    LDSFLUSH(0, z, zd);
    #undef LDSFLUSH

    __syncthreads();
    // dump table -> tblout[((b*128+s)*BPB+blk)*224 + f]
    for (int i = tid; i < SLOTS * SLOTF4; i += 1024) {
        const int s = i / SLOTF4;
        const int f = i - s * SLOTF4;
        tblout[(((size_t)b * SLOTS + s) * BPB + blk) * SLOTF4 + f] = tbl[i];
    }
}

// =========================================================================
// K2: reduce per-block tables -> full bins. Wave w owns (b,gx); reads BPB
// contiguous records (streaming), flushes once to the 3 plane bins.
// Record layout: [4][56] transposed; channel c at (c&3)*56 + (c>>2);
// den at offset 49.
// =========================================================================

__global__ __launch_bounds__(256) void table_reduce_kernel(
    const float* __restrict__ tblout,
    float* __restrict__ nw, float* __restrict__ dn, int B) {
    const int lane = threadIdx.x & 63;
    const int w = blockIdx.x * 4 + (threadIdx.x >> 6);
    if (w >= B * SLOTS) return;
    const int b = w >> 7;
    const int gx = w & 127;
    const bool ld = (lane < NC4);

    const float* base = tblout + ((size_t)(b * SLOTS + gx) * BPB) * SLOTF4;
    float a0 = 0.f, a1 = 0.f, a2 = 0.f, a3 = 0.f, den = 0.f;
    for (int r = 0; r < BPB; ++r) {
        const float* rec = base + (size_t)r * SLOTF4;
        if (ld) {
            a0 += rec[lane];
            a1 += rec[56 + lane];
            a2 += rec[112 + lane];
            a3 += rec[168 + lane];
        }
        if (lane == 0) den += rec[49];
    }

    const int cells[3] = { gx * GRID_SZ, gx * GRID_SZ, 0 };
    #pragma unroll
    for (int p = 0; p < 3; ++p) {
        const int bin = (b * 3 + p) * G2 + cells[p];
        float* dst = nw + (size_t)bin * NC + 4 * lane;
        if (ld) {
            unsafeAtomicAdd(dst + 0, a0);
            unsafeAtomicAdd(dst + 1, a1);
            unsafeAtomicAdd(dst + 2, a2);
            unsafeAtomicAdd(dst + 3, a3);
        }
        if (lane == 0) unsafeAtomicAdd(dn + bin, den);
    }
}

// =========================================================================
// K3: transpose + normalize (full layout)
// =========================================================================

#define TCELLS 64
__global__ __launch_bounds__(256) void xpose_kernel(const float* __restrict__ nw,
                                                    const float* __restrict__ dn,
                                                    float* __restrict__ out) {
    __shared__ float tile[TCELLS][197];   // pad: conflict-free column reads
    __shared__ float dinv[TCELLS];
    const int t = threadIdx.x;
    const int pg = blockIdx.x >> 8;              // plane index (256 tiles/plane)
    const int c0 = (blockIdx.x & 255) * TCELLS;  // first cell of tile

    const float* src = nw + ((size_t)pg * G2 + c0) * NC;
    for (int i = t; i < TCELLS * NC4; i += 256) {
        const int cell = i / NC4;
        const int cp = i - cell * NC4;
        float4 v = ((const float4*)(src + (size_t)cell * NC))[cp];
        float* dst = &tile[cell][cp * 4];
        dst[0] = v.x; dst[1] = v.y; dst[2] = v.z; dst[3] = v.w;
    }
    if (t < TCELLS) dinv[t] = 1.0f / fmaxf(dn[pg * G2 + c0 + t], 1e-6f);
    __syncthreads();

    float* obase = out + (size_t)pg * NC * G2 + c0;
    for (int i = t; i < TCELLS * NC; i += 256) {
        const int c = i >> 6;
        const int cell = i & 63;
        obase[(size_t)c * G2 + cell] = tile[cell][c] * dinv[cell];
    }
}

// ---------------- utility ----------------

__global__ void zero_kernel(float4* __restrict__ p, long long n4) {
    long long i = (long long)blockIdx.x * blockDim.x + threadIdx.x;
    long long stride = (long long)gridDim.x * blockDim.x;
    const float4 z = make_float4(0.f, 0.f, 0.f, 0.f);
    for (; i < n4; i += stride) p[i] = z;
}

// ---------------- fallback (direct channel-major, R1-style) ----------------

struct Slot { int tag; float den; float4 acc; };

__device__ __forceinline__ void slot_flush(const Slot& s, float* __restrict__ out,
                                           float* __restrict__ den,
                                           size_t outPlaneBase, int denPlaneBase, int lane) {
    if (s.tag < 0) return;
    if (lane < NC4) {
        size_t base = outPlaneBase + (size_t)(4 * lane) * G2 + (size_t)s.tag;
        unsafeAtomicAdd(out + base,                s.acc.x);
        unsafeAtomicAdd(out + base + (size_t)G2,   s.acc.y);
        unsafeAtomicAdd(out + base + (size_t)2*G2, s.acc.z);
        unsafeAtomicAdd(out + base + (size_t)3*G2, s.acc.w);
    }
    if (lane == 0) unsafeAtomicAdd(den + denPlaneBase + s.tag, s.den);
}

__device__ __forceinline__ void plane_acc(Slot& a, Slot& b, int cell, float alpha,
                                          const float4& av,
                                          float* __restrict__ out, float* __restrict__ den,
                                          size_t outPlaneBase, int denPlaneBase, int lane) {
    if (cell == a.tag) {
        a.acc.x += av.x; a.acc.y += av.y; a.acc.z += av.z; a.acc.w += av.w; a.den += alpha;
    } else if (cell == b.tag) {
        b.acc.x += av.x; b.acc.y += av.y; b.acc.z += av.z; b.acc.w += av.w; b.den += alpha;
    } else {
        if (b.den > a.den) { Slot t = a; a = b; b = t; }
        slot_flush(b, out, den, outPlaneBase, denPlaneBase, lane);
        b.tag = cell; b.den = alpha; b.acc = av;
    }
}

__global__ __launch_bounds__(256) void splat_kernel(
    const float* __restrict__ gs, const float* __restrict__ sb,
    float* __restrict__ out, float* __restrict__ den, int B, int N, int ppw) {
    const int lane = threadIdx.x & 63;
    const long long wave = (long long)blockIdx.x * (blockDim.x >> 6) + (threadIdx.x >> 6);
    const long long totalPts = (long long)B * N;
    long long start = wave * ppw;
    if (start >= totalPts) return;
    long long end = start + ppw;
    if (end > totalPts) end = totalPts;
    const int bb = (int)(start / N);

    const float lo0 = sb[0], hi0 = sb[1];
    const float lo1 = sb[2], hi1 = sb[3];
    const float lo2 = sb[4], hi2 = sb[5];
    const float s0 = 2.0f / (hi0 - lo0);
    const float s1 = 2.0f / (hi1 - lo1);
    const float s2 = 2.0f / (hi2 - lo2);

    const size_t ob0 = ((size_t)(bb * 3 + 0) * NC) * G2;
    const size_t ob1 = ((size_t)(bb * 3 + 1) * NC) * G2;
    const size_t ob2 = ((size_t)(bb * 3 + 2) * NC) * G2;
    const int db0 = (bb * 3 + 0) * G2;
    const int db1 = (bb * 3 + 1) * G2;
    const int db2 = (bb * 3 + 2) * G2;

    const float4 f40 = make_float4(0.f, 0.f, 0.f, 0.f);
    Slot a0{-1,0.f,f40}, t0{-1,0.f,f40}, a1{-1,0.f,f40}, t1{-1,0.f,f40},
         a2{-1,0.f,f40}, t2{-1,0.f,f40};

    const float4* rows = (const float4*)gs;
    const float4* r0 = rows + (size_t)start * NC4;
    float4 v = (lane < NC4) ? r0[lane] : f40;
    float4 h = r0[0];

    for (long long i = start; i < end; ++i) {
        float4 vn = f40, hn = f40;
        if (i + 1 < end) {
            const float4* rn = rows + (size_t)(i + 1) * NC4;
            vn = (lane < NC4) ? rn[lane] : f40;
            hn = rn[0];
        }
        const float cnx = (h.x - lo0) * s0 - 1.0f;
        const float cny = (h.y - lo1) * s1 - 1.0f;
        const float cnz = (h.z - lo2) * s2 - 1.0f;
        int gx = (int)((cnx * 0.5f + 0.5f) * 127.0f);
        int gy = (int)((cny * 0.5f + 0.5f) * 127.0f);
        int gz = (int)((cnz * 0.5f + 0.5f) * 127.0f);
        gx = min(127, max(0, gx)); gy = min(127, max(0, gy)); gz = min(127, max(0, gz));
        const int cxy = __builtin_amdgcn_readfirstlane(gx * GRID_SZ + gy);
        const int cxz = __builtin_amdgcn_readfirstlane(gx * GRID_SZ + gz);
        const int cyz = __builtin_amdgcn_readfirstlane(gy * GRID_SZ + gz);
        const float alpha = 1.0f / (1.0f + __expf(-h.w));
        float4 vv = v;
        if (lane == 0) { vv.x = cnx; vv.y = cny; vv.z = cnz; }
        const float4 av = make_float4(vv.x*alpha, vv.y*alpha, vv.z*alpha, vv.w*alpha);
        plane_acc(a0, t0, cxy, alpha, av, out, den, ob0, db0, lane);
        plane_acc(a1, t1, cxz, alpha, av, out, den, ob1, db1, lane);
        plane_acc(a2, t2, cyz, alpha, av, out, den, ob2, db2, lane);
        v = vn; h = hn;
    }
    slot_flush(a0, out, den, ob0, db0, lane);
    slot_flush(t0, out, den, ob0, db0, lane);
    slot_flush(a1, out, den, ob1, db1, lane);
    slot_flush(t1, out, den, ob1, db1, lane);
    slot_flush(a2, out, den, ob2, db2, lane);
    slot_flush(t2, out, den, ob2, db2, lane);
}

__global__ void normalize_kernel(float* __restrict__ out, const float* __restrict__ den,
                                 int total4) {
    int idx = blockIdx.x * blockDim.x + threadIdx.x;
    const int stride = gridDim.x * blockDim.x;
    for (; idx < total4; idx += stride) {
        float4 v = ((float4*)out)[idx];
        const int e = idx * 4;
        const int cell = e & (G2 - 1);
        const int bp = e / (NC * G2);
        const float4 d = *(const float4*)(den + bp * G2 + cell);
        v.x /= fmaxf(d.x, 1e-6f);
        v.y /= fmaxf(d.y, 1e-6f);
        v.z /= fmaxf(d.z, 1e-6f);
        v.w /= fmaxf(d.w, 1e-6f);
        ((float4*)out)[idx] = v;
    }
}

// ---------------- launch ----------------

extern "C" void kernel_launch(void* const* d_in, const int* in_sizes, int n_in,
                              void* d_out, int out_size, void* d_ws, size_t ws_size,
                              hipStream_t stream) {
    const float* gs = (const float*)d_in[0];
    const float* sb = (const float*)d_in[1];
    float* out = (float*)d_out;

    const int B = out_size / (3 * NC * G2);                            // 4
    const int N = (int)((long long)in_sizes[0] / ((long long)B * NC)); // 131072
    const int NB = B * 3 * G2;                                         // 196608

    const size_t nwF = (size_t)NB * NC;                   // 38.5M floats
    const size_t dnF = (size_t)NB;                        // 196K floats
    const size_t tblF = (size_t)B * SLOTS * BPB * SLOTF4; // 7.34M floats (29 MB)
    size_t off = 0;
    const size_t o_nw = off;    off += nwF * 4;
    const size_t o_dn = off;    off += dnF * 4;
    const size_t o_tbl = off;   off += tblF * 4;
    const size_t need = off;

    if (ws_size >= need && (N % (BPB * AW)) == 0 && B >= 1) {
        char* ws = (char*)d_ws;
        float* nw = (float*)(ws + o_nw);
        float* dn = (float*)(ws + o_dn);
        float* tblout = (float*)(ws + o_tbl);

        // zero full bins (nw + dn contiguous)
        zero_kernel<<<4096, 256, 0, stream>>>((float4*)nw,
                                              (long long)(nwF + dnF) / 4);

        const int aBlocks = B * BPB;                       // 256
        lds_accum_kernel<<<aBlocks, 1024, 0, stream>>>(gs, sb, nw, dn, tblout, N);

        const int rWaves = B * SLOTS;                      // 512
        const int rBlocks = (rWaves + 3) / 4;              // 128
        table_reduce_kernel<<<rBlocks, 256, 0, stream>>>(tblout, nw, dn, B);

        const int xblocks = B * 3 * (G2 / TCELLS);         // 3072
        xpose_kernel<<<xblocks, 256, 0, stream>>>(nw, dn, out);
    } else {
        float* den = (float*)d_ws;
        const long long out4 = (long long)out_size / 4;
        const long long den4 = (long long)dnF / 4;
        const int ppw = 64;
        const long long waves = ((long long)B * N) / ppw;
        const int blocks = (int)((waves + 3) / 4);
        zero_kernel<<<2048, 256, 0, stream>>>((float4*)out, out4);
        zero_kernel<<<256, 256, 0, stream>>>((float4*)den, den4);
        splat_kernel<<<blocks, 256, 0, stream>>>(gs, sb, out, den, B, N, ppw);
        normalize_kernel<<<4096, 256, 0, stream>>>(out, den, (int)out4);
    }
}

// Round 18
// 351.388 us; speedup vs baseline: 1.5836x; 1.5836x over previous
//
#include <hip/hip_runtime.h>
#include <math.h>

#define GRID_SZ 128
#define NC 196
#define NC4 49                // NC/4 float4 per row
#define G2 (GRID_SZ*GRID_SZ)  // 16384
#define BPB 64                // blocks per batch in accum
#define SLOTS 128             // LDS table slots (one per gx, gy=gz=0)
#define SLOTF 200             // floats per slot (196 acc + den + pad)
#define AW 16                 // waves per accum block (1024 threads)

// =========================================================================
// K1: streaming accumulation.
// Block = 16 waves (1024 thr), 1 block/CU (100 KB LDS table).
// Scalar channel loads (ch = lane + 64k): head channels arrive in the first
// load -> shfl/cell critical path starts after 4 cache lines, not 13.
// Hot keys (gy==gz==0, ~97.7% of points):
//   gx==0   (~50%) -> per-wave register accumulator (no LDS ops)
//   gx==127 (~16%) -> per-wave register accumulator (clamp spike)
//   gx==cache tag  -> per-wave sticky register cache
//   cache miss     -> flush cache slot to LDS table (atomicAdd, stride-1)
// Tail (~2.3%): direct global atomics to full per-plane bins.
// Depth-4 batched prefetch: 16 scalar loads in flight per wave.
// =========================================================================

__device__ __forceinline__ void lds_flush(float* __restrict__ tbl, int tag,
                                          float v0, float v1, float v2, float v3,
                                          float d, int lane, bool l4) {
    float* slot = tbl + tag * SLOTF;
    atomicAdd(slot + lane, v0);
    atomicAdd(slot + 64 + lane, v1);
    atomicAdd(slot + 128 + lane, v2);
    if (l4) atomicAdd(slot + 192 + lane, v3);
    if (lane == 4) atomicAdd(slot + 196, d);
}

__global__ __launch_bounds__(1024, 1) void lds_accum_kernel(
    const float* __restrict__ gs, const float* __restrict__ sb,
    float* __restrict__ nw, float* __restrict__ dn,
    float* __restrict__ tblout, int N) {
    __shared__ float tbl[SLOTS * SLOTF];   // 102400 B

    const int tid = threadIdx.x;
    const int lane = tid & 63;
    const int widx = tid >> 6;

    for (int i = tid; i < SLOTS * SLOTF; i += 1024) tbl[i] = 0.f;
    __syncthreads();

    const int b = blockIdx.x / BPB;
    const int blk = blockIdx.x % BPB;
    const int strip = N / BPB;            // points per block (2048)
    const int cnt = strip / AW;           // points per wave (128)
    const long long p0 = (long long)b * N + (long long)blk * strip
                       + (long long)widx * cnt;

    const float lo0 = sb[0], hi0 = sb[1];
    const float lo1 = sb[2], hi1 = sb[3];
    const float lo2 = sb[4], hi2 = sb[5];
    const float s0 = 2.0f / (hi0 - lo0);
    const float s1 = 2.0f / (hi1 - lo1);
    const float s2 = 2.0f / (hi2 - lo2);

    const float* rows = gs + (size_t)p0 * NC;
    const bool l4 = (lane < 4);

    #define LOADP(J, V0, V1, V2, V3)                                   \
        {                                                              \
            const float* r_ = rows + (size_t)(J) * NC;                 \
            V0 = r_[lane];                                             \
            V1 = r_[64 + lane];                                        \
            V2 = r_[128 + lane];                                       \
            V3 = l4 ? r_[192 + lane] : 0.f;                            \
        }

    // pipeline slots A..D = points j..j+3
    float a0, a1, a2, a3, b0, b1, b2, b3;
    float c0_, c1_, c2_, c3_, d0, d1, d2, d3;
    {
        const int i1 = (cnt > 1) ? 1 : 0;
        const int i2 = (cnt > 2) ? 2 : 0;
        const int i3 = (cnt > 3) ? 3 : 0;
        LOADP(0, a0, a1, a2, a3);
        LOADP(i1, b0, b1, b2, b3);
        LOADP(i2, c0_, c1_, c2_, c3_);
        LOADP(i3, d0, d1, d2, d3);
    }

    // register accumulators
    float z0 = 0.f, z1 = 0.f, z2 = 0.f, z3 = 0.f, zd = 0.f;          // gx==0
    float y0 = 0.f, y1 = 0.f, y2 = 0.f, y3 = 0.f, yd = 0.f;          // gx==127
    int ctag = -1;                                                    // sticky
    float cc0 = 0.f, cc1 = 0.f, cc2 = 0.f, cc3 = 0.f, ccd = 0.f;

    #define CONSUME(V0, V1, V2, V3)                                          \
        {                                                                    \
            const float hx = __shfl(V0, 0);                                  \
            const float hy = __shfl(V0, 1);                                  \
            const float hz = __shfl(V0, 2);                                  \
            const float hw = __shfl(V0, 3);                                  \
            const float cnx = (hx - lo0) * s0 - 1.0f;                        \
            const float cny = (hy - lo1) * s1 - 1.0f;                        \
            const float cnz = (hz - lo2) * s2 - 1.0f;                        \
            int gx = (int)((cnx * 0.5f + 0.5f) * 127.0f);                    \
            int gy = (int)((cny * 0.5f + 0.5f) * 127.0f);                    \
            int gz = (int)((cnz * 0.5f + 0.5f) * 127.0f);                    \
            gx = min(127, max(0, gx));                                       \
            gy = min(127, max(0, gy));                                       \
            gz = min(127, max(0, gz));                                       \
            const float alpha = 1.0f / (1.0f + __expf(-hw));                 \
            float v0 = V0;                                                   \
            if (lane == 0) v0 = cnx;                                         \
            else if (lane == 1) v0 = cny;                                    \
            else if (lane == 2) v0 = cnz;                                    \
            const float av0 = v0 * alpha;                                    \
            const float av1 = (V1) * alpha;                                  \
            const float av2 = (V2) * alpha;                                  \
            const float av3 = (V3) * alpha;                                  \
            if ((gy | gz) == 0) {                                            \
                if (gx == 0) {                                               \
                    z0 += av0; z1 += av1; z2 += av2; z3 += av3; zd += alpha; \
                } else if (gx == 127) {                                      \
                    y0 += av0; y1 += av1; y2 += av2; y3 += av3; yd += alpha; \
                } else if (gx == ctag) {                                     \
                    cc0 += av0; cc1 += av1; cc2 += av2; cc3 += av3;          \
                    ccd += alpha;                                            \
                } else {                                                     \
                    if (ctag > 0)                                            \
                        lds_flush(tbl, ctag, cc0, cc1, cc2, cc3, ccd,        \
                                  lane, l4);                                 \
                    ctag = gx;                                               \
                    cc0 = av0; cc1 = av1; cc2 = av2; cc3 = av3;              \
                    ccd = alpha;                                             \
                }                                                            \
            } else {                                                         \
                const int cells[3] = { gx * GRID_SZ + gy, gx * GRID_SZ + gz, \
                                       gy * GRID_SZ + gz };                  \
                _Pragma("unroll")                                            \
                for (int p = 0; p < 3; ++p) {                                \
                    const int bin = (b * 3 + p) * G2 + cells[p];             \
                    float* dst = nw + (size_t)bin * NC;                      \
                    unsafeAtomicAdd(dst + lane, av0);                        \
                    unsafeAtomicAdd(dst + 64 + lane, av1);                   \
                    unsafeAtomicAdd(dst + 128 + lane, av2);                  \
                    if (l4) unsafeAtomicAdd(dst + 192 + lane, av3);          \
                    if (lane == 4) unsafeAtomicAdd(dn + bin, alpha);         \
                }                                                            \
            }                                                                \
        }

    for (int j = 0; j < cnt; j += 4) {
        // batch-issue loads for points j+4..j+7 (clamped; redundant at tail)
        float e0, e1, e2, e3, f0, f1, f2, f3;
        float g0, g1, g2, g3, h0, h1, h2, h3;
        const int j4 = (j + 4 < cnt) ? j + 4 : cnt - 1;
        const int j5 = (j + 5 < cnt) ? j + 5 : cnt - 1;
        const int j6 = (j + 6 < cnt) ? j + 6 : cnt - 1;
        const int j7 = (j + 7 < cnt) ? j + 7 : cnt - 1;
        LOADP(j4, e0, e1, e2, e3);
        LOADP(j5, f0, f1, f2, f3);
        LOADP(j6, g0, g1, g2, g3);
        LOADP(j7, h0, h1, h2, h3);

        // consume current group (loaded last iteration)
        CONSUME(a0, a1, a2, a3);
        CONSUME(b0, b1, b2, b3);
        CONSUME(c0_, c1_, c2_, c3_);
        CONSUME(d0, d1, d2, d3);

        // rotate
        a0 = e0; a1 = e1; a2 = e2; a3 = e3;
        b0 = f0; b1 = f1; b2 = f2; b3 = f3;
        c0_ = g0; c1_ = g1; c2_ = g2; c3_ = g3;
        d0 = h0; d1 = h1; d2 = h2; d3 = h3;
    }
    #undef CONSUME
    #undef LOADP

    // final flushes
    if (ctag > 0) lds_flush(tbl, ctag, cc0, cc1, cc2, cc3, ccd, lane, l4);
    lds_flush(tbl, 127, y0, y1, y2, y3, yd, lane, l4);
    lds_flush(tbl, 0, z0, z1, z2, z3, zd, lane, l4);

    __syncthreads();
    // dump table: record (b,gx) for this block -> tblout[((b*128+s)*BPB+blk)*200+f]
    for (int i = tid; i < SLOTS * SLOTF; i += 1024) {
        const int s = i / SLOTF;
        const int f = i - s * SLOTF;
        tblout[(((size_t)b * SLOTS + s) * BPB + blk) * SLOTF + f] = tbl[i];
    }
}

// =========================================================================
// K2: reduce per-block tables -> full bins. Wave w owns (b,gx); reads BPB
// contiguous records (streaming), flushes once to the 3 plane bins.
// =========================================================================

__global__ __launch_bounds__(256) void table_reduce_kernel(
    const float* __restrict__ tblout,
    float* __restrict__ nw, float* __restrict__ dn, int B) {
    const int lane = threadIdx.x & 63;
    const int w = blockIdx.x * 4 + (threadIdx.x >> 6);
    if (w >= B * SLOTS) return;
    const int b = w >> 7;
    const int gx = w & 127;
    const bool l4 = (lane < 4);

    const float* base = tblout + ((size_t)(b * SLOTS + gx) * BPB) * SLOTF;
    float a0 = 0.f, a1 = 0.f, a2 = 0.f, a3 = 0.f, den = 0.f;
    for (int r = 0; r < BPB; ++r) {
        const float* rec = base + (size_t)r * SLOTF;
        a0 += rec[lane];
        a1 += rec[64 + lane];
        a2 += rec[128 + lane];
        if (l4) a3 += rec[192 + lane];
        if (lane == 4) den += rec[196];
    }

    const int cells[3] = { gx * GRID_SZ, gx * GRID_SZ, 0 };
    #pragma unroll
    for (int p = 0; p < 3; ++p) {
        const int bin = (b * 3 + p) * G2 + cells[p];
        float* dst = nw + (size_t)bin * NC;
        unsafeAtomicAdd(dst + lane, a0);
        unsafeAtomicAdd(dst + 64 + lane, a1);
        unsafeAtomicAdd(dst + 128 + lane, a2);
        if (l4) unsafeAtomicAdd(dst + 192 + lane, a3);
        if (lane == 4) unsafeAtomicAdd(dn + bin, den);
    }
}

// =========================================================================
// K3: transpose + normalize (full layout)
// =========================================================================

#define TCELLS 64
__global__ __launch_bounds__(256) void xpose_kernel(const float* __restrict__ nw,
                                                    const float* __restrict__ dn,
                                                    float* __restrict__ out) {
    __shared__ float tile[TCELLS][197];   // pad: conflict-free column reads
    __shared__ float dinv[TCELLS];
    const int t = threadIdx.x;
    const int pg = blockIdx.x >> 8;              // plane index (256 tiles/plane)
    const int c0 = (blockIdx.x & 255) * TCELLS;  // first cell of tile

    const float* src = nw + ((size_t)pg * G2 + c0) * NC;
    for (int i = t; i < TCELLS * NC4; i += 256) {
        const int cell = i / NC4;
        const int cp = i - cell * NC4;
        float4 v = ((const float4*)(src + (size_t)cell * NC))[cp];
        float* dst = &tile[cell][cp * 4];
        dst[0] = v.x; dst[1] = v.y; dst[2] = v.z; dst[3] = v.w;
    }
    if (t < TCELLS) dinv[t] = 1.0f / fmaxf(dn[pg * G2 + c0 + t], 1e-6f);
    __syncthreads();

    float* obase = out + (size_t)pg * NC * G2 + c0;
    for (int i = t; i < TCELLS * NC; i += 256) {
        const int c = i >> 6;
        const int cell = i & 63;
        obase[(size_t)c * G2 + cell] = tile[cell][c] * dinv[cell];
    }
}

// ---------------- utility ----------------

__global__ void zero_kernel(float4* __restrict__ p, long long n4) {
    long long i = (long long)blockIdx.x * blockDim.x + threadIdx.x;
    long long stride = (long long)gridDim.x * blockDim.x;
    const float4 z = make_float4(0.f, 0.f, 0.f, 0.f);
    for (; i < n4; i += stride) p[i] = z;
}

// ---------------- fallback (direct channel-major, R1-style) ----------------

struct Slot { int tag; float den; float4 acc; };

__device__ __forceinline__ void slot_flush(const Slot& s, float* __restrict__ out,
                                           float* __restrict__ den,
                                           size_t outPlaneBase, int denPlaneBase, int lane) {
    if (s.tag < 0) return;
    if (lane < NC4) {
        size_t base = outPlaneBase + (size_t)(4 * lane) * G2 + (size_t)s.tag;
        unsafeAtomicAdd(out + base,                s.acc.x);
        unsafeAtomicAdd(out + base + (size_t)G2,   s.acc.y);
        unsafeAtomicAdd(out + base + (size_t)2*G2, s.acc.z);
        unsafeAtomicAdd(out + base + (size_t)3*G2, s.acc.w);
    }
    if (lane == 0) unsafeAtomicAdd(den + denPlaneBase + s.tag, s.den);
}

__device__ __forceinline__ void plane_acc(Slot& a, Slot& b, int cell, float alpha,
                                          const float4& av,
                                          float* __restrict__ out, float* __restrict__ den,
                                          size_t outPlaneBase, int denPlaneBase, int lane) {
    if (cell == a.tag) {
        a.acc.x += av.x; a.acc.y += av.y; a.acc.z += av.z; a.acc.w += av.w; a.den += alpha;
    } else if (cell == b.tag) {
        b.acc.x += av.x; b.acc.y += av.y; b.acc.z += av.z; b.acc.w += av.w; b.den += alpha;
    } else {
        if (b.den > a.den) { Slot t = a; a = b; b = t; }
        slot_flush(b, out, den, outPlaneBase, denPlaneBase, lane);
        b.tag = cell; b.den = alpha; b.acc = av;
    }
}

__global__ __launch_bounds__(256) void splat_kernel(
    const float* __restrict__ gs, const float* __restrict__ sb,
    float* __restrict__ out, float* __restrict__ den, int B, int N, int ppw) {
    const int lane = threadIdx.x & 63;
    const long long wave = (long long)blockIdx.x * (blockDim.x >> 6) + (threadIdx.x >> 6);
    const long long totalPts = (long long)B * N;
    long long start = wave * ppw;
    if (start >= totalPts) return;
    long long end = start + ppw;
    if (end > totalPts) end = totalPts;
    const int bb = (int)(start / N);

    const float lo0 = sb[0], hi0 = sb[1];
    const float lo1 = sb[2], hi1 = sb[3];
    const float lo2 = sb[4], hi2 = sb[5];
    const float s0 = 2.0f / (hi0 - lo0);
    const float s1 = 2.0f / (hi1 - lo1);
    const float s2 = 2.0f / (hi2 - lo2);

    const size_t ob0 = ((size_t)(bb * 3 + 0) * NC) * G2;
    const size_t ob1 = ((size_t)(bb * 3 + 1) * NC) * G2;
    const size_t ob2 = ((size_t)(bb * 3 + 2) * NC) * G2;
    const int db0 = (bb * 3 + 0) * G2;
    const int db1 = (bb * 3 + 1) * G2;
    const int db2 = (bb * 3 + 2) * G2;

    const float4 f40 = make_float4(0.f, 0.f, 0.f, 0.f);
    Slot a0{-1,0.f,f40}, t0{-1,0.f,f40}, a1{-1,0.f,f40}, t1{-1,0.f,f40},
         a2{-1,0.f,f40}, t2{-1,0.f,f40};

    const float4* rows = (const float4*)gs;
    const float4* r0 = rows + (size_t)start * NC4;
    float4 v = (lane < NC4) ? r0[lane] : f40;
    float4 h = r0[0];

    for (long long i = start; i < end; ++i) {
        float4 vn = f40, hn = f40;
        if (i + 1 < end) {
            const float4* rn = rows + (size_t)(i + 1) * NC4;
            vn = (lane < NC4) ? rn[lane] : f40;
            hn = rn[0];
        }
        const float cnx = (h.x - lo0) * s0 - 1.0f;
        const float cny = (h.y - lo1) * s1 - 1.0f;
        const float cnz = (h.z - lo2) * s2 - 1.0f;
        int gx = (int)((cnx * 0.5f + 0.5f) * 127.0f);
        int gy = (int)((cny * 0.5f + 0.5f) * 127.0f);
        int gz = (int)((cnz * 0.5f + 0.5f) * 127.0f);
        gx = min(127, max(0, gx)); gy = min(127, max(0, gy)); gz = min(127, max(0, gz));
        const int cxy = __builtin_amdgcn_readfirstlane(gx * GRID_SZ + gy);
        const int cxz = __builtin_amdgcn_readfirstlane(gx * GRID_SZ + gz);
        const int cyz = __builtin_amdgcn_readfirstlane(gy * GRID_SZ + gz);
        const float alpha = 1.0f / (1.0f + __expf(-h.w));
        float4 vv = v;
        if (lane == 0) { vv.x = cnx; vv.y = cny; vv.z = cnz; }
        const float4 av = make_float4(vv.x*alpha, vv.y*alpha, vv.z*alpha, vv.w*alpha);
        plane_acc(a0, t0, cxy, alpha, av, out, den, ob0, db0, lane);
        plane_acc(a1, t1, cxz, alpha, av, out, den, ob1, db1, lane);
        plane_acc(a2, t2, cyz, alpha, av, out, den, ob2, db2, lane);
        v = vn; h = hn;
    }
    slot_flush(a0, out, den, ob0, db0, lane);
    slot_flush(t0, out, den, ob0, db0, lane);
    slot_flush(a1, out, den, ob1, db1, lane);
    slot_flush(t1, out, den, ob1, db1, lane);
    slot_flush(a2, out, den, ob2, db2, lane);
    slot_flush(t2, out, den, ob2, db2, lane);
}

__global__ void normalize_kernel(float* __restrict__ out, const float* __restrict__ den,
                                 int total4) {
    int idx = blockIdx.x * blockDim.x + threadIdx.x;
    const int stride = gridDim.x * blockDim.x;
    for (; idx < total4; idx += stride) {
        float4 v = ((float4*)out)[idx];
        const int e = idx * 4;
        const int cell = e & (G2 - 1);
        const int bp = e / (NC * G2);
        const float4 d = *(const float4*)(den + bp * G2 + cell);
        v.x /= fmaxf(d.x, 1e-6f);
        v.y /= fmaxf(d.y, 1e-6f);
        v.z /= fmaxf(d.z, 1e-6f);
        v.w /= fmaxf(d.w, 1e-6f);
        ((float4*)out)[idx] = v;
    }
}

// ---------------- launch ----------------

extern "C" void kernel_launch(void* const* d_in, const int* in_sizes, int n_in,
                              void* d_out, int out_size, void* d_ws, size_t ws_size,
                              hipStream_t stream) {
    const float* gs = (const float*)d_in[0];
    const float* sb = (const float*)d_in[1];
    float* out = (float*)d_out;

    const int B = out_size / (3 * NC * G2);                            // 4
    const int N = (int)((long long)in_sizes[0] / ((long long)B * NC)); // 131072
    const int NB = B * 3 * G2;                                         // 196608

    const size_t nwF = (size_t)NB * NC;                  // 38.5M floats
    const size_t dnF = (size_t)NB;                       // 196K floats
    const size_t tblF = (size_t)B * SLOTS * BPB * SLOTF; // 6.55M floats (26 MB)
    size_t off = 0;
    const size_t o_nw = off;    off += nwF * 4;
    const size_t o_dn = off;    off += dnF * 4;
    const size_t o_tbl = off;   off += tblF * 4;
    const size_t need = off;

    if (ws_size >= need && (N % (BPB * AW)) == 0 && B >= 1) {
        char* ws = (char*)d_ws;
        float* nw = (float*)(ws + o_nw);
        float* dn = (float*)(ws + o_dn);
        float* tblout = (float*)(ws + o_tbl);

        // zero full bins (nw + dn contiguous)
        zero_kernel<<<4096, 256, 0, stream>>>((float4*)nw,
                                              (long long)(nwF + dnF) / 4);

        const int aBlocks = B * BPB;                       // 256
        lds_accum_kernel<<<aBlocks, 1024, 0, stream>>>(gs, sb, nw, dn, tblout, N);

        const int rWaves = B * SLOTS;                      // 512
        const int rBlocks = (rWaves + 3) / 4;              // 128
        table_reduce_kernel<<<rBlocks, 256, 0, stream>>>(tblout, nw, dn, B);

        const int xblocks = B * 3 * (G2 / TCELLS);         // 3072
        xpose_kernel<<<xblocks, 256, 0, stream>>>(nw, dn, out);
    } else {
        float* den = (float*)d_ws;
        const long long out4 = (long long)out_size / 4;
        const long long den4 = (long long)dnF / 4;
        const int ppw = 64;
        const long long waves = ((long long)B * N) / ppw;
        const int blocks = (int)((waves + 3) / 4);
        zero_kernel<<<2048, 256, 0, stream>>>((float4*)out, out4);
        zero_kernel<<<256, 256, 0, stream>>>((float4*)den, den4);
        splat_kernel<<<blocks, 256, 0, stream>>>(gs, sb, out, den, B, N, ppw);
        normalize_kernel<<<4096, 256, 0, stream>>>(out, den, (int)out4);
    }
}